// Round 7
// baseline (343.012 us; speedup 1.0000x reference)
//
#include <hip/hip_runtime.h>
#include <hip/hip_bf16.h>

#define FDIM 128
#define BROWS 64     // i1 rows per bucket: bin = i1>>6, loc = i1&63 (6-bit pack)
#define NBLK 128     // partition blocks for hist/scatter (runs of 16 = 1 line/block)

// ---- bf16 helpers (manual, RNE) ----
static __device__ __forceinline__ unsigned short f2bf(float x) {
    unsigned u = __float_as_uint(x);
    unsigned r = 0x7fffu + ((u >> 16) & 1u);
    return (unsigned short)((u + r) >> 16);
}
static __device__ __forceinline__ float bf_lo(unsigned u) { return __uint_as_float(u << 16); }
static __device__ __forceinline__ float bf_hi(unsigned u) { return __uint_as_float(u & 0xffff0000u); }

// ---- k1: fused histogram + make_ws.
// Blocks [0,NBLK): LDS histogram of i1 buckets -> M[k][b] (coalesced dump).
// Blocks [NBLK, NBLK+8): Ws = W + W^T (16384 elems over 8 blocks).
__global__ __launch_bounds__(512) void k_hist_ws(
    const int* __restrict__ idx, int E, int nb, unsigned* __restrict__ M,
    const float* __restrict__ W, float* __restrict__ Ws) {
    extern __shared__ unsigned cnt[];
    int bid = blockIdx.x;
    if (bid < NBLK) {
        for (int i = threadIdx.x; i < nb; i += 512) cnt[i] = 0;
        __syncthreads();
        int chunk = (E + NBLK - 1) / NBLK;
        int s = bid * chunk;
        int e_end = min(E, s + chunk);
        for (int e = s + threadIdx.x; e < e_end; e += 512) {
            int i1 = idx[E + e];
            atomicAdd(&cnt[i1 >> 6], 1u);
        }
        __syncthreads();
        for (int i = threadIdx.x; i < nb; i += 512)
            M[(size_t)bid * nb + i] = cnt[i];
    } else {
        int base = (bid - NBLK) * 2048;
        for (int k = threadIdx.x; k < 2048; k += 512) {
            int e = base + k;
            int i = e >> 7, j = e & 127;
            Ws[e] = W[i * FDIM + j] + W[j * FDIM + i];
        }
    }
}

// ---- k2: G = F @ Ws (bf16 out) ----
__global__ __launch_bounds__(256, 2) void gemm_g(
    const float* __restrict__ Fm, const float* __restrict__ Ws,
    unsigned short* __restrict__ Gbf, int N) {
    __shared__ float sWs[FDIM * FDIM];
    __shared__ float sF[32][FDIM];

    for (int k = threadIdx.x; k < FDIM * FDIM / 4; k += 256)
        ((float4*)sWs)[k] = ((const float4*)Ws)[k];

    int row0 = blockIdx.x * 32;
    for (int k = threadIdx.x; k < 32 * FDIM / 4; k += 256) {
        int r = k >> 5, c = k & 31;
        int gr = row0 + r;
        float4 v = make_float4(0.f, 0.f, 0.f, 0.f);
        if (gr < N) v = ((const float4*)Fm)[(size_t)gr * (FDIM / 4) + c];
        ((float4*)&sF[r][0])[c] = v;
    }
    __syncthreads();

    int tx = threadIdx.x & 31;
    int ty = threadIdx.x >> 5;
    int c0 = tx * 4;
    float acc[4][4] = {};

    for (int i = 0; i < FDIM; ++i) {
        float4 w = *(const float4*)&sWs[i * FDIM + c0];
        float f0 = sF[ty * 4 + 0][i];
        float f1 = sF[ty * 4 + 1][i];
        float f2 = sF[ty * 4 + 2][i];
        float f3 = sF[ty * 4 + 3][i];
        acc[0][0] = fmaf(f0, w.x, acc[0][0]); acc[0][1] = fmaf(f0, w.y, acc[0][1]);
        acc[0][2] = fmaf(f0, w.z, acc[0][2]); acc[0][3] = fmaf(f0, w.w, acc[0][3]);
        acc[1][0] = fmaf(f1, w.x, acc[1][0]); acc[1][1] = fmaf(f1, w.y, acc[1][1]);
        acc[1][2] = fmaf(f1, w.z, acc[1][2]); acc[1][3] = fmaf(f1, w.w, acc[1][3]);
        acc[2][0] = fmaf(f2, w.x, acc[2][0]); acc[2][1] = fmaf(f2, w.y, acc[2][1]);
        acc[2][2] = fmaf(f2, w.z, acc[2][2]); acc[2][3] = fmaf(f2, w.w, acc[2][3]);
        acc[3][0] = fmaf(f3, w.x, acc[3][0]); acc[3][1] = fmaf(f3, w.y, acc[3][1]);
        acc[3][2] = fmaf(f3, w.z, acc[3][2]); acc[3][3] = fmaf(f3, w.w, acc[3][3]);
    }

    for (int r = 0; r < 4; ++r) {
        int gr = row0 + ty * 4 + r;
        if (gr < N) {
            ushort4 o;
            o.x = f2bf(acc[r][0]); o.y = f2bf(acc[r][1]);
            o.z = f2bf(acc[r][2]); o.w = f2bf(acc[r][3]);
            *(ushort4*)(Gbf + (size_t)gr * FDIM + c0) = o;
        }
    }
}

// ---- k3: fused btot + exclusive scan + per-bucket cursor prefix, ONE block.
// M[k][b] counts -> M[k][b] cursor starts; bucketStart[0..nb]. ----
__global__ __launch_bounds__(256) void k_scan(unsigned* __restrict__ M, int nb,
                                              unsigned* __restrict__ bucketStart) {
    __shared__ unsigned wS[4];
    __shared__ unsigned carry;
    int t = threadIdx.x, lane = t & 63, wid = t >> 6;
    if (t == 0) carry = 0;
    __syncthreads();
    int rounds = (nb + 255) / 256;
    for (int r = 0; r < rounds; ++r) {
        int b = r * 256 + t;
        unsigned v = 0;
        if (b < nb) {
            #pragma unroll
            for (int k = 0; k < NBLK; k += 8) {
                unsigned t0 = M[(size_t)(k + 0) * nb + b];
                unsigned t1 = M[(size_t)(k + 1) * nb + b];
                unsigned t2 = M[(size_t)(k + 2) * nb + b];
                unsigned t3 = M[(size_t)(k + 3) * nb + b];
                unsigned t4 = M[(size_t)(k + 4) * nb + b];
                unsigned t5 = M[(size_t)(k + 5) * nb + b];
                unsigned t6 = M[(size_t)(k + 6) * nb + b];
                unsigned t7 = M[(size_t)(k + 7) * nb + b];
                v += t0 + t1 + t2 + t3 + t4 + t5 + t6 + t7;
            }
        }
        unsigned incl = v;
        for (int d = 1; d < 64; d <<= 1) {
            unsigned u = __shfl_up(incl, d, 64);
            if (lane >= d) incl += u;
        }
        if (lane == 63) wS[wid] = incl;
        __syncthreads();
        unsigned wOff = carry;
        for (int i = 0; i < wid; ++i) wOff += wS[i];
        unsigned start = wOff + incl - v;
        if (b < nb) {
            bucketStart[b] = start;
            unsigned run = start;
            #pragma unroll
            for (int k = 0; k < NBLK; k += 8) {
                unsigned t0 = M[(size_t)(k + 0) * nb + b];
                unsigned t1 = M[(size_t)(k + 1) * nb + b];
                unsigned t2 = M[(size_t)(k + 2) * nb + b];
                unsigned t3 = M[(size_t)(k + 3) * nb + b];
                unsigned t4 = M[(size_t)(k + 4) * nb + b];
                unsigned t5 = M[(size_t)(k + 5) * nb + b];
                unsigned t6 = M[(size_t)(k + 6) * nb + b];
                unsigned t7 = M[(size_t)(k + 7) * nb + b];
                M[(size_t)(k + 0) * nb + b] = run; run += t0;
                M[(size_t)(k + 1) * nb + b] = run; run += t1;
                M[(size_t)(k + 2) * nb + b] = run; run += t2;
                M[(size_t)(k + 3) * nb + b] = run; run += t3;
                M[(size_t)(k + 4) * nb + b] = run; run += t4;
                M[(size_t)(k + 5) * nb + b] = run; run += t5;
                M[(size_t)(k + 6) * nb + b] = run; run += t6;
                M[(size_t)(k + 7) * nb + b] = run; run += t7;
            }
        }
        __syncthreads();
        if (t == 0) carry = carry + wS[0] + wS[1] + wS[2] + wS[3];
        __syncthreads();
    }
    if (t == 0) bucketStart[nb] = carry;
}

// ---- k4: scatter via LDS cursors; each block writes 16-entry runs = whole lines ----
__global__ __launch_bounds__(512) void k_scatter(const int* __restrict__ idx,
                                                 const int* __restrict__ mol, int E,
                                                 int nb, const unsigned* __restrict__ M,
                                                 unsigned* __restrict__ sortedE) {
    extern __shared__ unsigned cur[];
    int bid = blockIdx.x;
    for (int i = threadIdx.x; i < nb; i += 512)
        cur[i] = M[(size_t)bid * nb + i];
    __syncthreads();
    int chunk = (E + NBLK - 1) / NBLK;
    int s = bid * chunk;
    int e_end = min(E, s + chunk);
    for (int e = s + threadIdx.x; e < e_end; e += 512) {
        int i0 = idx[e];
        int i1 = idx[E + e];
        int m  = mol[e];
        int b  = i1 >> 6;
        int loc = i1 & 63;
        unsigned pos = atomicAdd(&cur[b], 1u);
        sortedE[pos] = (unsigned)i0 | ((unsigned)m << 16) | ((unsigned)loc << 26);
    }
}

// ---- k5: edge kernel. One WG per bucket: 64-row F window (fp32->bf16) in LDS,
// gather G, accumulate per-molecule in LDS smol, flush with plain stores. ----
__global__ __launch_bounds__(256) void edge_kernel(
    const unsigned short* __restrict__ Gbf, const float* __restrict__ Fm,
    const unsigned* __restrict__ sortedE, const unsigned* __restrict__ bucketStart,
    float* __restrict__ part, int N, int Mout) {
    __shared__ unsigned short sFrow[BROWS * FDIM];   // 16 KB
    __shared__ float smol[1024];                     // 4 KB

    int b = blockIdx.x;
    int row0 = b * BROWS;
    int nrow = min(BROWS, N - row0);
    for (int k = threadIdx.x; k < nrow * (FDIM / 4); k += 256) {
        int r = k >> 5, c = k & 31;             // c indexes float4 within row
        float4 v = ((const float4*)(Fm + (size_t)(row0 + r) * FDIM))[c];
        ushort4 o;
        o.x = f2bf(v.x); o.y = f2bf(v.y); o.z = f2bf(v.z); o.w = f2bf(v.w);
        *(ushort4*)(sFrow + r * FDIM + c * 4) = o;
    }
    for (int i = threadIdx.x; i < 1024; i += 256) smol[i] = 0.f;
    __syncthreads();

    const int s = bucketStart[b];
    const int e_end = bucketStart[b + 1];
    const int lane = threadIdx.x & 63;
    const int sub  = lane >> 4;
    const int t16  = lane & 15;
    const int off16 = t16 * 8;
    const int wid  = threadIdx.x >> 6;

    for (int base = s + wid * 4; base < e_end; base += 16) {
        int e = base + sub;
        bool valid = (e < e_end);
        unsigned pk = valid ? sortedE[e] : 0u;
        int i0  = pk & 0xffff;
        int m   = (pk >> 16) & 0x3ff;
        int loc = pk >> 26;
        const uint4 g = *(const uint4*)(Gbf + (size_t)i0 * FDIM + off16);
        const uint4 f = *(const uint4*)(sFrow + loc * FDIM + off16);
        float p;
        p = bf_lo(g.x) * bf_lo(f.x);
        p = fmaf(bf_hi(g.x), bf_hi(f.x), p);
        p = fmaf(bf_lo(g.y), bf_lo(f.y), p);
        p = fmaf(bf_hi(g.y), bf_hi(f.y), p);
        p = fmaf(bf_lo(g.z), bf_lo(f.z), p);
        p = fmaf(bf_hi(g.z), bf_hi(f.z), p);
        p = fmaf(bf_lo(g.w), bf_lo(f.w), p);
        p = fmaf(bf_hi(g.w), bf_hi(f.w), p);
        p += __shfl_xor(p, 1, 16);
        p += __shfl_xor(p, 2, 16);
        p += __shfl_xor(p, 4, 16);
        p += __shfl_xor(p, 8, 16);
        if (t16 == 0 && valid) atomicAdd(&smol[m], p);
    }
    __syncthreads();
    float* prow = part + (size_t)b * 1024;
    for (int i = threadIdx.x; i < 1024; i += 256) prow[i] = smol[i];
}

// ---- k6: single-dispatch reduction: 16 blocks, block bb owns 64 outputs ----
__global__ __launch_bounds__(256) void k_red(const float* __restrict__ part, int nb,
                                             float* __restrict__ out, int Mout) {
    __shared__ float red[256];
    int bb = blockIdx.x, t = threadIdx.x;
    int m = bb * 64 + (t & 63);
    int sl = t >> 6;          // 0..3
    float s = 0.f;
    for (int b = sl; b < nb; b += 4)
        s += part[(size_t)b * 1024 + m];
    red[t] = s;
    __syncthreads();
    if (t < 64 && m < Mout)
        out[m] = red[t] + red[t + 64] + red[t + 128] + red[t + 192];
}

extern "C" void kernel_launch(void* const* d_in, const int* in_sizes, int n_in,
                              void* d_out, int out_size, void* d_ws, size_t ws_size,
                              hipStream_t stream) {
    const float* Fm = (const float*)d_in[0];
    const float* W  = (const float*)d_in[1];
    const int* idx  = (const int*)d_in[2];
    const int* mol  = (const int*)d_in[3];
    float* out = (float*)d_out;

    const int N = in_sizes[0] / FDIM;   // 50000
    const int E = in_sizes[3];          // 1600000

    const int nb = (N + BROWS - 1) / BROWS;   // 782 buckets

    // workspace layout (~23 MB)
    char* ws = (char*)d_ws;
    size_t o = 0;
    float* Ws = (float*)(ws + o);                    o += 64 * 1024;
    unsigned short* Gbf = (unsigned short*)(ws + o); o += ((size_t)N * FDIM * 2 + 255) & ~(size_t)255;
    unsigned* sortedE = (unsigned*)(ws + o);         o += ((size_t)E * 4 + 255) & ~(size_t)255;
    unsigned* M = (unsigned*)(ws + o);               o += ((size_t)NBLK * nb * 4 + 255) & ~(size_t)255;
    unsigned* bucketStart = (unsigned*)(ws + o);     o += ((size_t)(nb + 1) * 4 + 255) & ~(size_t)255;
    float* part = (float*)(ws + o);                  o += (size_t)nb * 1024 * sizeof(float);

    size_t smem = (size_t)nb * 4;
    k_hist_ws<<<NBLK + 8, 512, smem, stream>>>(idx, E, nb, M, W, Ws);
    gemm_g<<<(N + 31) / 32, 256, 0, stream>>>(Fm, Ws, Gbf, N);
    k_scan<<<1, 256, 0, stream>>>(M, nb, bucketStart);
    k_scatter<<<NBLK, 512, smem, stream>>>(idx, mol, E, nb, M, sortedE);
    edge_kernel<<<nb, 256, 0, stream>>>(Gbf, Fm, sortedE, bucketStart, part, N, out_size);
    k_red<<<16, 256, 0, stream>>>(part, nb, out, out_size);
}